// Round 1
// baseline (85.143 us; speedup 1.0000x reference)
//
#include <hip/hip_runtime.h>
#include <hip/hip_bf16.h>

// Problem constants: B=128, C=21, L=2048, W=32, S=8, O=16, NW=252, NK=4032, K=672
#define Bb   128
#define Cc   21
#define Ll   2048
#define Ss   8
#define Oo   16
#define NWw  252
#define NKk  4032
#define Kk   672
#define KP   680   // LDS pitch (bf16): 85 x 16B granules/row, conflict-light b128

typedef __attribute__((ext_vector_type(8))) short  short8;  // 8 bf16 = 4 VGPRs
typedef __attribute__((ext_vector_type(4))) float  f32x4;

static __device__ __forceinline__ unsigned short f2bf(float f) {
    union { __hip_bfloat16 h; unsigned short u; } cv;
    cv.h = __float2bfloat16(f);
    return cv.u;
}

static __device__ __forceinline__ short8 cvt8(const float4 a0, const float4 a1) {
    short8 a;
    a[0] = (short)f2bf(a0.x); a[1] = (short)f2bf(a0.y);
    a[2] = (short)f2bf(a0.z); a[3] = (short)f2bf(a0.w);
    a[4] = (short)f2bf(a1.x); a[5] = (short)f2bf(a1.y);
    a[6] = (short)f2bf(a1.z); a[7] = (short)f2bf(a1.w);
    return a;
}

// R8 = session optimum (83.7 us total, kernel ~26 us), reinstalled after
// R9 (L2 warm pass), R10 (physical transpose), R11 (re-block) all regressed.
// R12 (this round): L2-pollution theory. Per-XCD L2 working set was
//   x-slab 3.01 MB (4x inter-window reuse, MUST stay resident)
// + w stream 1.35 MB (single-use, zero reuse)
// + out 0.13 MB (write-only)
// = 4.5 MB > 4 MB L2 -> the weight stream evicts x before its reuse,
// inflating x HBM fetch well past the compulsory 22 MB.
// Fix: non-temporal hints on the two zero-reuse streams (w loads, out
// stores) so they bypass L2; x keeps normal caching. Hint-only diff vs R8.
// Structure (unchanged):
//  - single dispatch, compulsory bytes only (x 22 + w 10.8 + out 2 = 35 MB);
//  - grid 256 (252 windows + 4 idle), XCD r=bid%8 owns windows [32r,32r+32)
//    -> 3.1 MB fp32 x-slab per XCD reused within-kernel in L2 (R4's win);
//  - 512 thr = 8 waves x 16-batch m-tiles = all 128 batches; w staged ONCE
//    per window fp32->bf16 into LDS (R7: per-wave B redundancy costs ~4 us);
//  - whole A-slice batch-issued before the single barrier (21 float4-pairs
//    in flight), cvt'd in-register, then a pure 21-MFMA sweep.
__global__ __launch_bounds__(512)
void fb_fwd(const float* __restrict__ x, const float* __restrict__ w,
            float* __restrict__ out) {
    __shared__ unsigned short ws[Oo * KP];   // 21.8 KB

    const int bid = blockIdx.x;
    const int j   = (bid & 7) * 32 + (bid >> 3);          // XCD-grouped window
    if (j >= NWw) return;                                  // 4 tail blocks idle
    const int s    = (j < NWw - 1) ? j * Ss : (Ll - 32);  // STARTS[j], mult of 8
    const int tid  = threadIdx.x;
    const int lane = tid & 63;
    const int wv   = tid >> 6;       // 0..7: m-tile id (16 batch rows)
    const int col  = lane & 15;      // MFMA m-row (A) / n-col (B = w-row o)
    const int quad = lane >> 4;      // k-chunk selector

    // ---- batch-issue the whole A-slice (21 x 32 B fp32, all in flight) ----
    const float* xrow = x + ((size_t)(wv * 16 + col) * Cc) * Ll + s + quad * 8;
    float4 a0[Cc], a1[Cc];
#pragma unroll
    for (int c = 0; c < Cc; ++c) {
        a0[c] = *(const float4*)(xrow + (size_t)c * Ll);
        a1[c] = *(const float4*)(xrow + (size_t)c * Ll + 4);
    }

    // ---- stage weight[j]: 16 x 672 fp32 -> bf16 LDS, [o][k] (B^T) ----
    // Non-temporal: each w[j] tile is read by exactly ONE block chip-wide;
    // caching it in L2 only evicts the reused x slab.
    {
        const f32x4* wj4 = (const f32x4*)(w + (size_t)j * Oo * Kk);
        for (int t = tid; t < Oo * (Kk / 4); t += 512) {   // 2688 float4
            f32x4 v = __builtin_nontemporal_load(wj4 + t);
            int o = t / (Kk / 4);                           // Kk/4 = 168
            int r = t - o * (Kk / 4);
            *(ushort4*)&ws[o * KP + r * 4] =
                make_ushort4(f2bf(v[0]), f2bf(v[1]), f2bf(v[2]), f2bf(v[3]));
        }
    }

    // cvt A to bf16 frags while the stage drains
    short8 afr[Cc];
#pragma unroll
    for (int c = 0; c < Cc; ++c) afr[c] = cvt8(a0[c], a1[c]);

    __syncthreads();

    const unsigned short* wrow = &ws[col * KP + quad * 8];
    f32x4 acc = {0.f, 0.f, 0.f, 0.f};
#pragma unroll
    for (int c = 0; c < Cc; ++c)
        acc = __builtin_amdgcn_mfma_f32_16x16x32_bf16(
            afr[c], *(const short8*)(wrow + c * 32), acc, 0, 0, 0);

    // ---- C/D layout: col = lane&15, row = quad*4 + reg ----
    // Non-temporal stores: out is write-only, no reuse -> keep it out of L2.
    const int rbase = wv * 16 + quad * 4;
    float* op = out + (size_t)rbase * NKk + j * 16 + col;
#pragma unroll
    for (int r = 0; r < 4; ++r)
        __builtin_nontemporal_store(acc[r], &op[(size_t)r * NKk]);
}

extern "C" void kernel_launch(void* const* d_in, const int* in_sizes, int n_in,
                              void* d_out, int out_size, void* d_ws, size_t ws_size,
                              hipStream_t stream) {
    const float* x = (const float*)d_in[0];   // (128, 21, 2048) fp32
    const float* w = (const float*)d_in[1];   // (4032, 672) fp32
    float* out = (float*)d_out;               // (128, 4032) fp32
    fb_fwd<<<dim3(256), dim3(512), 0, stream>>>(x, w, out);
}

// Round 2
// 81.809 us; speedup vs baseline: 1.0408x; 1.0408x over previous
//
#include <hip/hip_runtime.h>
#include <hip/hip_bf16.h>

// Problem constants: B=128, C=21, L=2048, W=32, S=8, O=16, NW=252, NK=4032, K=672
#define Bb   128
#define Cc   21
#define Ll   2048
#define Ss   8
#define Oo   16
#define NWw  252
#define NKk  4032
#define Kk   672
#define KP   680   // LDS pitch (bf16): 85 x 16B granules/row, conflict-light b128

typedef __attribute__((ext_vector_type(8))) short  short8;  // 8 bf16 = 4 VGPRs
typedef __attribute__((ext_vector_type(4))) float  f32x4;

static __device__ __forceinline__ unsigned short f2bf(float f) {
    union { __hip_bfloat16 h; unsigned short u; } cv;
    cv.h = __float2bfloat16(f);
    return cv.u;
}

static __device__ __forceinline__ short8 cvt8(const float4 a0, const float4 a1) {
    short8 a;
    a[0] = (short)f2bf(a0.x); a[1] = (short)f2bf(a0.y);
    a[2] = (short)f2bf(a0.z); a[3] = (short)f2bf(a0.w);
    a[4] = (short)f2bf(a1.x); a[5] = (short)f2bf(a1.y);
    a[6] = (short)f2bf(a1.z); a[7] = (short)f2bf(a1.w);
    return a;
}

// R8 = session optimum; R9-R11 structural variants regressed; R12 NT hints
// neutral (L2-pollution theory dead: fetch already compulsory).
// R13 (this round): LATENCY theory. The rolled weight-stage loop
//   for(t=tid;t<2688;t+=512){load;cvt;ds_write;}
// serializes ~6 iterations, each paying a full s_waitcnt vmcnt round trip
// through a memory queue that is µs-deep during the chip-wide t=0 burst
// (97 MB demanded at once). 6 serial queue trips ~= the unexplained ~18 µs.
// Fix: hand-batch the stage -- issue all 5-6 w loads into registers FIRST
// (w feeds the barrier, earliest consumer), then the 42 x loads, then
// cvt+ds_write the in-flight w data (vmcnt is in-order: consuming w waits
// only on the first 6 loads, not the x burst). One queue trip, not six.
// Structure otherwise unchanged:
//  - single dispatch, compulsory bytes only (x 22 + w 10.8 + out 2 = 35 MB);
//  - grid 256 (252 windows + 4 idle), XCD r=bid%8 owns windows [32r,32r+32)
//    -> 3.1 MB fp32 x-slab per XCD reused within-kernel in L2 (R4's win);
//  - 512 thr = 8 waves x 16-batch m-tiles = all 128 batches; w staged ONCE
//    per window fp32->bf16 into LDS (R7);
//  - whole A-slice batch-issued (21 float4-pairs in flight), cvt'd in
//    register, then a pure 21-MFMA sweep.
__global__ __launch_bounds__(512)
void fb_fwd(const float* __restrict__ x, const float* __restrict__ w,
            float* __restrict__ out) {
    __shared__ unsigned short ws[Oo * KP];   // 21.8 KB

    const int bid = blockIdx.x;
    const int j   = (bid & 7) * 32 + (bid >> 3);          // XCD-grouped window
    if (j >= NWw) return;                                  // 4 tail blocks idle
    const int s    = (j < NWw - 1) ? j * Ss : (Ll - 32);  // STARTS[j], mult of 8
    const int tid  = threadIdx.x;
    const int lane = tid & 63;
    const int wv   = tid >> 6;       // 0..7: m-tile id (16 batch rows)
    const int col  = lane & 15;      // MFMA m-row (A) / n-col (B = w-row o)
    const int quad = lane >> 4;      // k-chunk selector

    // ---- batch-issue ALL weight-stage loads first (5-6 float4 per thread),
    //      they feed the barrier that gates every wave ----
    const f32x4* wj4 = (const f32x4*)(w + (size_t)j * Oo * Kk);
    const bool has6 = tid < (Oo * (Kk / 4) - 5 * 512);     // tid < 128
    f32x4 wv0 = __builtin_nontemporal_load(wj4 + tid);
    f32x4 wv1 = __builtin_nontemporal_load(wj4 + tid + 512);
    f32x4 wv2 = __builtin_nontemporal_load(wj4 + tid + 1024);
    f32x4 wv3 = __builtin_nontemporal_load(wj4 + tid + 1536);
    f32x4 wv4 = __builtin_nontemporal_load(wj4 + tid + 2048);
    f32x4 wv5;
    if (has6) wv5 = __builtin_nontemporal_load(wj4 + tid + 2560);

    // ---- batch-issue the whole A-slice (21 x 32 B fp32, all in flight) ----
    const float* xrow = x + ((size_t)(wv * 16 + col) * Cc) * Ll + s + quad * 8;
    float4 a0[Cc], a1[Cc];
#pragma unroll
    for (int c = 0; c < Cc; ++c) {
        a0[c] = *(const float4*)(xrow + (size_t)c * Ll);
        a1[c] = *(const float4*)(xrow + (size_t)c * Ll + 4);
    }

    // ---- cvt + LDS-write the staged w (waits only on the 6 w loads:
    //      vmcnt completion is in-order, w was issued first) ----
    {
        int t;
        t = tid;        { int o = t / (Kk / 4); int r = t - o * (Kk / 4);
            *(ushort4*)&ws[o * KP + r * 4] =
                make_ushort4(f2bf(wv0[0]), f2bf(wv0[1]), f2bf(wv0[2]), f2bf(wv0[3])); }
        t = tid + 512;  { int o = t / (Kk / 4); int r = t - o * (Kk / 4);
            *(ushort4*)&ws[o * KP + r * 4] =
                make_ushort4(f2bf(wv1[0]), f2bf(wv1[1]), f2bf(wv1[2]), f2bf(wv1[3])); }
        t = tid + 1024; { int o = t / (Kk / 4); int r = t - o * (Kk / 4);
            *(ushort4*)&ws[o * KP + r * 4] =
                make_ushort4(f2bf(wv2[0]), f2bf(wv2[1]), f2bf(wv2[2]), f2bf(wv2[3])); }
        t = tid + 1536; { int o = t / (Kk / 4); int r = t - o * (Kk / 4);
            *(ushort4*)&ws[o * KP + r * 4] =
                make_ushort4(f2bf(wv3[0]), f2bf(wv3[1]), f2bf(wv3[2]), f2bf(wv3[3])); }
        t = tid + 2048; { int o = t / (Kk / 4); int r = t - o * (Kk / 4);
            *(ushort4*)&ws[o * KP + r * 4] =
                make_ushort4(f2bf(wv4[0]), f2bf(wv4[1]), f2bf(wv4[2]), f2bf(wv4[3])); }
        if (has6) {
            t = tid + 2560;  int o = t / (Kk / 4); int r = t - o * (Kk / 4);
            *(ushort4*)&ws[o * KP + r * 4] =
                make_ushort4(f2bf(wv5[0]), f2bf(wv5[1]), f2bf(wv5[2]), f2bf(wv5[3]));
        }
    }

    // cvt A to bf16 frags while the rest of the x burst drains
    short8 afr[Cc];
#pragma unroll
    for (int c = 0; c < Cc; ++c) afr[c] = cvt8(a0[c], a1[c]);

    __syncthreads();

    const unsigned short* wrow = &ws[col * KP + quad * 8];
    f32x4 acc = {0.f, 0.f, 0.f, 0.f};
#pragma unroll
    for (int c = 0; c < Cc; ++c)
        acc = __builtin_amdgcn_mfma_f32_16x16x32_bf16(
            afr[c], *(const short8*)(wrow + c * 32), acc, 0, 0, 0);

    // ---- C/D layout: col = lane&15, row = quad*4 + reg ----
    // Non-temporal stores: out is write-only, no reuse -> keep it out of L2.
    const int rbase = wv * 16 + quad * 4;
    float* op = out + (size_t)rbase * NKk + j * 16 + col;
#pragma unroll
    for (int r = 0; r < 4; ++r)
        __builtin_nontemporal_store(acc[r], &op[(size_t)r * NKk]);
}

extern "C" void kernel_launch(void* const* d_in, const int* in_sizes, int n_in,
                              void* d_out, int out_size, void* d_ws, size_t ws_size,
                              hipStream_t stream) {
    const float* x = (const float*)d_in[0];   // (128, 21, 2048) fp32
    const float* w = (const float*)d_in[1];   // (4032, 672) fp32
    float* out = (float*)d_out;               // (128, 4032) fp32
    fb_fwd<<<dim3(256), dim3(512), 0, stream>>>(x, w, out);
}

// Round 3
// 81.380 us; speedup vs baseline: 1.0462x; 1.0053x over previous
//
#include <hip/hip_runtime.h>
#include <hip/hip_bf16.h>

// Problem constants: B=128, C=21, L=2048, W=32, S=8, O=16, NW=252, NK=4032, K=672
#define Bb   128
#define Cc   21
#define Ll   2048
#define Ss   8
#define Oo   16
#define NWw  252
#define NKk  4032
#define Kk   672
#define KP   680   // LDS pitch (bf16) per o-row: conflict-light b128

typedef __attribute__((ext_vector_type(8))) short  short8;  // 8 bf16 = 4 VGPRs
typedef __attribute__((ext_vector_type(4))) float  f32x4;

static __device__ __forceinline__ unsigned short f2bf(float f) {
    union { __hip_bfloat16 h; unsigned short u; } cv;
    cv.h = __float2bfloat16(f);
    return cv.u;
}

static __device__ __forceinline__ short8 cvt8(const float4 a0, const float4 a1) {
    short8 a;
    a[0] = (short)f2bf(a0.x); a[1] = (short)f2bf(a0.y);
    a[2] = (short)f2bf(a0.z); a[3] = (short)f2bf(a0.w);
    a[4] = (short)f2bf(a1.x); a[5] = (short)f2bf(a1.y);
    a[6] = (short)f2bf(a1.z); a[7] = (short)f2bf(a1.w);
    return a;
}

// R14: in-block window-overlap reuse (R11 done right).
// History: R8 optimum (~24-26 us kernel); R9 warm / R10 transpose / R11
// re-block regressed; R12 NT neutral; R13 batched w-stage -3 us.
// Remaining theory: kernel ~= HBM drain at only ~1.4 TB/s effective because
// (a) x's 4x window reuse lives in a fragile 4 MB XCD-L2 shared with a
//     single-use w stream -- every eviction = extra HBM fetch;
// (b) requests are 2688 scattered 128 B segments per block.
// Fix: block = 4 consecutive windows x 32 batches (grid 63 groups x 4
// batch-quarters = 252). Per (row,c) the 4 windows consume chunks
// (ww+quad)*8 of one contiguous 56-float span -> all window reuse is
// merged in-block at L1/MSHR level; HBM x fetch compulsory BY CONSTRUCTION.
// x runs grow 128 B -> 224 B. All 4 w tiles staged once per block into LDS
// (87 KB); the 4 bq-blocks of a group sit on one XCD (bids differ by 8) so
// the 4x w re-read is L2-served -> w loads are CACHEABLE (NT would force
// 4x HBM w). Per-wave MFMA structure/layout identical to verified R8.
// XCD map: bid%8 = r owns groups [8r, 8r+8); adjacent groups same XCD so
// group-edge x chunks (24-float overlap) reuse in L2 too.
__global__ __launch_bounds__(512)
void fb_fwd(const float* __restrict__ x, const float* __restrict__ w,
            float* __restrict__ out) {
    __shared__ unsigned short ws[4 * Oo * KP];   // 87.0 KB

    const int bid = blockIdx.x;
    const int r   = bid & 7;            // XCD (round-robin assumption, R4)
    const int idx = bid >> 3;           // 0..31 within XCD
    const int g   = r * 8 + (idx >> 2); // window group (4 windows each)
    if (g > 62) return;                 // 4 idle blocks on XCD 7
    const int bq   = idx & 3;           // batch quarter (32 rows)
    const int tid  = threadIdx.x;
    const int lane = tid & 63;
    const int wv   = tid >> 6;          // 0..7
    const int wm   = wv >> 2;           // m-tile within block (0..1)
    const int ww   = wv & 3;            // window within group
    const int col  = lane & 15;         // MFMA m-row (A) / n-col (B = o)
    const int quad = lane >> 4;         // k-chunk selector
    const int j    = g * 4 + ww;        // global window id
    const int s_loc = (j < NWw - 1) ? ww * 8 : 32;  // j=251: start 2016

    // ---- phase 1: issue w-stage batch 1 (11 float4/thread, cacheable) ----
    const f32x4* wj4 = (const f32x4*)w + (size_t)g * 10752;  // 4 windows
    f32x4 wb[21];
#pragma unroll
    for (int p = 0; p < 11; ++p) wb[p] = wj4[tid + p * 512];

    // ---- phase 2: issue the whole A-slice (42 float4, all in flight) ----
    const int b = bq * 32 + wm * 16 + col;
    const float* xrow = x + ((size_t)b * Cc) * Ll + g * 32 + s_loc + quad * 8;
    float4 a0[Cc], a1[Cc];
#pragma unroll
    for (int c = 0; c < Cc; ++c) {
        a0[c] = *(const float4*)(xrow + (size_t)c * Ll);
        a1[c] = *(const float4*)(xrow + (size_t)c * Ll + 4);
    }

    // ---- phase 3: cvt + LDS-write w batch 1 (waits only its 11 loads) ----
#pragma unroll
    for (int p = 0; p < 11; ++p) {
        int t  = tid + p * 512;
        int oa = t / 168;               // (window,o) pair: 0..63
        int r4 = t - oa * 168;          // float4 index within 672-k row
        *(ushort4*)&ws[oa * KP + r4 * 4] =
            make_ushort4(f2bf(wb[p][0]), f2bf(wb[p][1]),
                         f2bf(wb[p][2]), f2bf(wb[p][3]));
    }

    // ---- phase 4: issue w-stage batch 2 (10 float4) ----
#pragma unroll
    for (int p = 11; p < 21; ++p) wb[p] = wj4[tid + p * 512];

    // ---- phase 5: cvt A to bf16 frags (waits x drain; w2 stays in flight) --
    short8 afr[Cc];
#pragma unroll
    for (int c = 0; c < Cc; ++c) afr[c] = cvt8(a0[c], a1[c]);

    // ---- phase 6: cvt + LDS-write w batch 2 ----
#pragma unroll
    for (int p = 11; p < 21; ++p) {
        int t  = tid + p * 512;
        int oa = t / 168;
        int r4 = t - oa * 168;
        *(ushort4*)&ws[oa * KP + r4 * 4] =
            make_ushort4(f2bf(wb[p][0]), f2bf(wb[p][1]),
                         f2bf(wb[p][2]), f2bf(wb[p][3]));
    }

    __syncthreads();

    // ---- 21-MFMA sweep: B-tile = this wave's window (ww) ----
    const unsigned short* wrow = &ws[(ww * Oo + col) * KP + quad * 8];
    f32x4 acc = {0.f, 0.f, 0.f, 0.f};
#pragma unroll
    for (int c = 0; c < Cc; ++c)
        acc = __builtin_amdgcn_mfma_f32_16x16x32_bf16(
            afr[c], *(const short8*)(wrow + c * 32), acc, 0, 0, 0);

    // ---- C/D layout: col = lane&15, row = quad*4 + reg (verified R8) ----
    const int rbase = bq * 32 + wm * 16 + quad * 4;
    float* op = out + (size_t)rbase * NKk + j * 16 + col;
#pragma unroll
    for (int rr = 0; rr < 4; ++rr)
        __builtin_nontemporal_store(acc[rr], &op[(size_t)rr * NKk]);
}

extern "C" void kernel_launch(void* const* d_in, const int* in_sizes, int n_in,
                              void* d_out, int out_size, void* d_ws, size_t ws_size,
                              hipStream_t stream) {
    const float* x = (const float*)d_in[0];   // (128, 21, 2048) fp32
    const float* w = (const float*)d_in[1];   // (4032, 672) fp32
    float* out = (float*)d_out;               // (128, 4032) fp32
    fb_fwd<<<dim3(256), dim3(512), 0, stream>>>(x, w, out);
}